// Round 1
// baseline (382.561 us; speedup 1.0000x reference)
//
#include <hip/hip_runtime.h>

typedef short bf16x8_t __attribute__((ext_vector_type(8)));
typedef float f32x4_t __attribute__((ext_vector_type(4)));

#define NTOK 577
#define NHEAD 12
#define HD 64
#define XROW 2304
#define NSTEP 19  // ceil(577/32)

__device__ __forceinline__ unsigned short f2bf(float f) {
  unsigned u = __builtin_bit_cast(unsigned, f);
  u += 0x7FFFu + ((u >> 16) & 1u);
  return (unsigned short)(u >> 16);
}

struct __align__(16) SMem {
  unsigned short q_s[32][72];      // q * (w*SCALE), bf16
  float qv_s[2][32][32];           // qv/qh: q-dot-rel-k tables, fp32
  unsigned char rm_s[640];         // spatial row of token m (24 = CLS, 255 = pad)
  unsigned char cm_s[640];         // spatial col of token m
  float l_s[32];                   // softmax denominators
  union {
    struct { unsigned short tk_s[2][32][72]; } pro;       // rel_k tables (prologue)
    struct {
      unsigned short k_s[32][72];                          // k * w
      unsigned short v_sT[64][40];                         // v transposed [d][m]
      unsigned short P_s[32][40];                          // exp(logits), bf16
    } loop;
    struct {
      float rs_s[2][32][32];                               // rowsums over spatial row/col groups
      float sv_f[2][32][32];                               // scattered table weights
      unsigned short sv_bf[2][32][40];
      unsigned short tvT_s[2][64][40];                     // rel_v tables transposed [d][t]
    } epi;
  } u;
};

extern "C" __global__ __launch_bounds__(256) void hma_kernel(
    const float* __restrict__ x, const float* __restrict__ wts,
    const float* __restrict__ tkv, const float* __restrict__ tkh,
    const float* __restrict__ tvv, const float* __restrict__ tvh,
    float* __restrict__ out) {
  __shared__ SMem sm;
  const int tid = threadIdx.x;
  const int wave = tid >> 6, lane = tid & 63, quad = lane >> 4, l15 = lane & 15;
  const int rg = wave & 1;      // row group (16 rows)
  const int cg = wave >> 1;     // col group
  const int tb_w = wave >> 1;   // table assignment for qv / rowsum MFMAs
  const int n0 = blockIdx.x * 32;
  const int h = blockIdx.y, b = blockIdx.z;

  const float w0 = wts[0], w1 = wts[1], w2 = wts[2];
  const float w = (h < 8) ? (w0 + w1 + w2) : ((h < 10) ? (w1 + w2) : w2);
  const float qscale = w * 0.125f;

  // ---- prologue: rm/cm, q, rel_k tables ----
  for (int m = tid; m < 640; m += 256) {
    int r, c;
    if (m == 0) { r = 24; c = 24; }
    else if (m < NTOK) { r = (m - 1) / 24; c = (m - 1) % 24; }
    else { r = 255; c = 255; }
    sm.rm_s[m] = (unsigned char)r;
    sm.cm_s[m] = (unsigned char)c;
  }
  const float* xb = x + (size_t)b * NTOK * XROW + h * HD;
  for (int pass = 0; pass < 2; ++pass) {
    int e4 = pass * 256 + tid;
    int row = e4 >> 4, col4 = e4 & 15;
    int n_g = n0 + row;
    float4 v = make_float4(0.f, 0.f, 0.f, 0.f);
    if (n_g < NTOK) v = *(const float4*)(xb + (size_t)n_g * XROW + col4 * 4);
    unsigned short* dst = &sm.q_s[row][col4 * 4];
    dst[0] = f2bf(v.x * qscale); dst[1] = f2bf(v.y * qscale);
    dst[2] = f2bf(v.z * qscale); dst[3] = f2bf(v.w * qscale);
  }
  for (int e4 = tid; e4 < 1024; e4 += 256) {
    int tb = e4 >> 9, r2 = e4 & 511, row = r2 >> 4, col4 = r2 & 15;
    const float* src = tb ? tkh : tkv;
    float4 v = make_float4(0.f, 0.f, 0.f, 0.f);
    if (row < 30) v = *(const float4*)(src + row * 64 + col4 * 4);
    unsigned short* dst = &sm.u.pro.tk_s[tb][row][col4 * 4];
    dst[0] = f2bf(v.x); dst[1] = f2bf(v.y); dst[2] = f2bf(v.z); dst[3] = f2bf(v.w);
  }
  __syncthreads();

  // ---- qv/qh = q_hat . rel_k_table^T (wave -> table tb_w, row group rg) ----
  for (int tt = 0; tt < 2; ++tt) {
    f32x4_t acc = {0.f, 0.f, 0.f, 0.f};
    for (int kk = 0; kk < 2; ++kk) {
      bf16x8_t a = *(const bf16x8_t*)&sm.q_s[rg * 16 + l15][kk * 32 + quad * 8];
      bf16x8_t bb = *(const bf16x8_t*)&sm.u.pro.tk_s[tb_w][tt * 16 + l15][kk * 32 + quad * 8];
      acc = __builtin_amdgcn_mfma_f32_16x16x32_bf16(a, bb, acc, 0, 0, 0);
    }
    for (int r = 0; r < 4; ++r)
      sm.qv_s[tb_w][rg * 16 + quad * 4 + r][tt * 16 + l15] = acc[r];
  }

  // per-lane row constants
  int rvh[4], cvh[4], nzf[4];
  for (int r = 0; r < 4; ++r) {
    int n_g = n0 + rg * 16 + quad * 4 + r;
    nzf[r] = (n_g == 0);
    int nm1 = (n_g > 0) ? (n_g - 1) : 0;
    rvh[r] = nm1 / 24;
    cvh[r] = nm1 % 24;
  }

  f32x4_t oacc[2] = {{0.f,0.f,0.f,0.f},{0.f,0.f,0.f,0.f}};
  f32x4_t rsacc[2] = {{0.f,0.f,0.f,0.f},{0.f,0.f,0.f,0.f}};
  const float* xk = xb + 768;
  const float* xv = xb + 1536;

  // ---- main K loop over m tiles ----
  for (int step = 0; step < NSTEP; ++step) {
    const int m0 = step * 32;
    __syncthreads();  // prev iter's reads of k_s/v_sT/P_s done
    for (int pass = 0; pass < 2; ++pass) {
      int e4 = pass * 256 + tid;
      int row = e4 >> 4, col4 = e4 & 15;
      int m_g = m0 + row;
      float4 kv = make_float4(0.f,0.f,0.f,0.f), vv = make_float4(0.f,0.f,0.f,0.f);
      if (m_g < NTOK) {
        kv = *(const float4*)(xk + (size_t)m_g * XROW + col4 * 4);
        vv = *(const float4*)(xv + (size_t)m_g * XROW + col4 * 4);
      }
      unsigned short* kd = &sm.u.loop.k_s[row][col4 * 4];
      kd[0] = f2bf(kv.x * w); kd[1] = f2bf(kv.y * w);
      kd[2] = f2bf(kv.z * w); kd[3] = f2bf(kv.w * w);
      int d0 = col4 * 4;
      sm.u.loop.v_sT[d0 + 0][row] = f2bf(vv.x);
      sm.u.loop.v_sT[d0 + 1][row] = f2bf(vv.y);
      sm.u.loop.v_sT[d0 + 2][row] = f2bf(vv.z);
      sm.u.loop.v_sT[d0 + 3][row] = f2bf(vv.w);
    }
    __syncthreads();  // staging visible
    // S = q_hat . k_hat^T  (16x16 per wave)
    f32x4_t s = {0.f, 0.f, 0.f, 0.f};
    for (int kk = 0; kk < 2; ++kk) {
      bf16x8_t a = *(const bf16x8_t*)&sm.q_s[rg * 16 + l15][kk * 32 + quad * 8];
      bf16x8_t bb = *(const bf16x8_t*)&sm.u.loop.k_s[cg * 16 + l15][kk * 32 + quad * 8];
      s = __builtin_amdgcn_mfma_f32_16x16x32_bf16(a, bb, s, 0, 0, 0);
    }
    // rel bias + exp -> P_s
    const int m_loc = cg * 16 + l15;
    const int m_g = m0 + m_loc;
    const int rmv = sm.rm_s[m_g], cmv = sm.cm_s[m_g];
    const int mz = (m_g == 0);
    const int mpad = (m_g >= NTOK);
    for (int r = 0; r < 4; ++r) {
      int n_loc = rg * 16 + quad * 4 + r;
      int iv, ih;
      if (nzf[r] | mz) { iv = 0; ih = 0; }
      else {
        int dv = rmv - rvh[r]; dv = dv < -14 ? -14 : (dv > 14 ? 14 : dv); iv = dv + 15;
        int dh = cmv - cvh[r]; dh = dh < -14 ? -14 : (dh > 14 ? 14 : dh); ih = dh + 15;
      }
      float logit = s[r] + sm.qv_s[0][n_loc][iv] + sm.qv_s[1][n_loc][ih];
      float p = __expf(logit);
      if (mpad) p = 0.f;
      sm.u.loop.P_s[n_loc][m_loc] = f2bf(p);
    }
    __syncthreads();  // P_s visible
    // O += P.V ; rowsum += P.G
    bf16x8_t a = *(const bf16x8_t*)&sm.u.loop.P_s[rg * 16 + l15][quad * 8];
    for (int sub = 0; sub < 2; ++sub) {
      bf16x8_t bb = *(const bf16x8_t*)&sm.u.loop.v_sT[cg * 32 + sub * 16 + l15][quad * 8];
      oacc[sub] = __builtin_amdgcn_mfma_f32_16x16x32_bf16(a, bb, oacc[sub], 0, 0, 0);
    }
    const unsigned char* gsrc = tb_w ? sm.cm_s : sm.rm_s;
    unsigned gw0 = *(const unsigned*)(gsrc + m0 + quad * 8);
    unsigned gw1 = *(const unsigned*)(gsrc + m0 + quad * 8 + 4);
    for (int gt = 0; gt < 2; ++gt) {
      const unsigned g = (unsigned)(gt * 16 + l15);
      bf16x8_t gb;
#pragma unroll
      for (int j = 0; j < 8; ++j) {
        unsigned byte = (j < 4) ? ((gw0 >> (8 * j)) & 255u) : ((gw1 >> (8 * (j - 4))) & 255u);
        gb[j] = (short)((byte == g) ? 0x3F80 : 0);  // bf16 1.0f
      }
      rsacc[gt] = __builtin_amdgcn_mfma_f32_16x16x32_bf16(a, gb, rsacc[gt], 0, 0, 0);
    }
  }

  // ---- epilogue ----
  __syncthreads();  // loop reads done; union switches to epi
  for (int gt = 0; gt < 2; ++gt)
    for (int r = 0; r < 4; ++r)
      sm.u.epi.rs_s[tb_w][rg * 16 + quad * 4 + r][gt * 16 + l15] = rsacc[gt][r];
  for (int e = tid; e < 2048; e += 256)
    (&sm.u.epi.sv_f[0][0][0])[e] = 0.f;
  for (int e = tid; e < 3840; e += 256) {
    int tb = e / 1920, r2 = e % 1920, t = r2 >> 6, d = r2 & 63;
    const float* src = tb ? tvh : tvv;
    sm.u.epi.tvT_s[tb][d][t] = f2bf(src[t * 64 + d]);
  }
  {
    int tb = tid >> 7, r2 = tid & 127, d = r2 >> 1, t = 30 + (r2 & 1);
    sm.u.epi.tvT_s[tb][d][t] = 0;  // zero table pad rows
  }
  __syncthreads();
  // scatter rowsums into table-index space; compute denominators
  for (int p = tid; p < 1600; p += 256) {
    int tb = p / 800, r2 = p % 800, n = r2 / 25, g = r2 % 25;
    float val = sm.u.epi.rs_s[tb][n][g];
    int n_g = n0 + n;
    int t;
    if (n_g == 0 || n_g >= NTOK || g == 24) t = 0;
    else {
      int base = tb ? ((n_g - 1) % 24) : ((n_g - 1) / 24);
      int dq = g - base; dq = dq < -14 ? -14 : (dq > 14 ? 14 : dq);
      t = dq + 15;
    }
    atomicAdd(&sm.u.epi.sv_f[tb][n][t], val);
  }
  if (tid < 32) {
    float l = 0.f;
    for (int g = 0; g < 25; ++g) l += sm.u.epi.rs_s[0][tid][g];
    sm.l_s[tid] = l;
  }
  __syncthreads();
  for (int e = tid; e < 2048; e += 256) {
    int tb = e >> 10, r2 = e & 1023, n = r2 >> 5, t = r2 & 31;
    sm.u.epi.sv_bf[tb][n][t] = f2bf(sm.u.epi.sv_f[tb][n][t]);
  }
  for (int sub = 0; sub < 2; ++sub)
    for (int r = 0; r < 4; ++r) oacc[sub][r] *= w;  // scale P.V part only
  __syncthreads();
  // O += sv . tvv^T + sh . tvh^T
  for (int tb = 0; tb < 2; ++tb) {
    bf16x8_t a = *(const bf16x8_t*)&sm.u.epi.sv_bf[tb][rg * 16 + l15][quad * 8];
    for (int sub = 0; sub < 2; ++sub) {
      bf16x8_t bb = *(const bf16x8_t*)&sm.u.epi.tvT_s[tb][cg * 32 + sub * 16 + l15][quad * 8];
      oacc[sub] = __builtin_amdgcn_mfma_f32_16x16x32_bf16(a, bb, oacc[sub], 0, 0, 0);
    }
  }
  // normalize + store
  float* ob = out + (size_t)b * NTOK * (NHEAD * HD) + h * HD;
  for (int r = 0; r < 4; ++r) {
    int n_loc = rg * 16 + quad * 4 + r;
    int n_g = n0 + n_loc;
    if (n_g < NTOK) {
      float inv = 1.f / sm.l_s[n_loc];
      for (int sub = 0; sub < 2; ++sub) {
        int d = cg * 32 + sub * 16 + l15;
        ob[(size_t)n_g * (NHEAD * HD) + d] = oacc[sub][r] * inv;
      }
    }
  }
}

extern "C" void kernel_launch(void* const* d_in, const int* in_sizes, int n_in,
                              void* d_out, int out_size, void* d_ws, size_t ws_size,
                              hipStream_t stream) {
  const float* x   = (const float*)d_in[0];
  const float* wts = (const float*)d_in[1];
  const float* tkv = (const float*)d_in[2];
  const float* tkh = (const float*)d_in[3];
  const float* tvv = (const float*)d_in[4];
  const float* tvh = (const float*)d_in[5];
  float* out = (float*)d_out;
  const int B = in_sizes[0] / (NTOK * XROW);
  dim3 grid(NSTEP, NHEAD, B);  // 19 row-tiles x 12 heads x B
  hma_kernel<<<grid, 256, 0, stream>>>(x, wts, tkv, tkh, tvv, tvh, out);
}

// Round 2
// 331.599 us; speedup vs baseline: 1.1537x; 1.1537x over previous
//
#include <hip/hip_runtime.h>

typedef short bf16x8_t __attribute__((ext_vector_type(8)));
typedef short bf16x4_t __attribute__((ext_vector_type(4)));
typedef float f32x4_t __attribute__((ext_vector_type(4)));

#define NTOK 577
#define NHEAD 12
#define HD 64
#define XROW 2304
#define NSTEP 19  // ceil(577/32)
#define VST 36    // v_sT column stride (shorts): 72B rows -> reads conflict-free, writes 4-way

__device__ __forceinline__ unsigned short f2bf(float f) {
  unsigned u = __builtin_bit_cast(unsigned, f);
  u += 0x7FFFu + ((u >> 16) & 1u);
  return (unsigned short)(u >> 16);
}

struct __align__(16) SMem {
  unsigned short q_s[32][72];      // q * (w^2*SCALE), bf16                     4608 B
  float qg_s[2][32][26];           // pre-scattered rel-k bias by group g       6656 B
  unsigned char rm_s[640];         // spatial row group of token m (24=CLS/pad) 640 B
  unsigned char cm_s[640];         // spatial col group                         640 B
  float l_s[32];                   // softmax denominators                      128 B
  union {                          //                                          19968 B
    struct { unsigned short tk_s[2][32][72]; float qv_t[2][32][32]; } pro;
    struct {
      unsigned short k_s[32][72];          // k (unscaled), bf16
      unsigned short v_sT[64][VST];        // v transposed [d][m]
      unsigned short P_s[32][40];          // exp(logits), bf16
    } loop;
    struct {
      float sv_f[2][32][30];               // scattered P-mass by table index t
      unsigned short sv_bf[2][32][32];
      unsigned short tvT_s[2][64][32];     // rel_v tables transposed [d][t]
    } epi;
  } u;
};  // total 32640 B -> 5 blocks/CU

extern "C" __global__ __launch_bounds__(256, 5) void hma_kernel(
    const float* __restrict__ x, const float* __restrict__ wts,
    const float* __restrict__ tkv, const float* __restrict__ tkh,
    const float* __restrict__ tvv, const float* __restrict__ tvh,
    float* __restrict__ out) {
  __shared__ SMem sm;
  const int tid = threadIdx.x;
  const int wave = tid >> 6, lane = tid & 63, quad = lane >> 4, l15 = lane & 15;
  const int rg = wave & 1;      // row group (16 rows of n)
  const int cg = wave >> 1;     // col group
  const int tb_w = wave >> 1;   // table assignment for qv / rowsum MFMAs
  const int n0 = blockIdx.x * 32;
  const int h = blockIdx.y, b = blockIdx.z;

  const float w0 = wts[0], w1 = wts[1], w2 = wts[2];
  const float w = (h < 8) ? (w0 + w1 + w2) : ((h < 10) ? (w1 + w2) : w2);
  const float qscale = w * w * 0.125f;   // w^2 * SCALE folded into q (k stays raw)
  const float inv_w = 1.0f / w;          // rel_k tables carry 1/w so bias gets w^1

  // ---- prologue: rm/cm, q, rel_k tables ----
  for (int m = tid; m < 640; m += 256) {
    int r, c;
    if (m == 0 || m >= NTOK) { r = 24; c = 24; }     // CLS and pad both -> group 24
    else { r = (m - 1) / 24; c = (m - 1) % 24; }
    sm.rm_s[m] = (unsigned char)r;
    sm.cm_s[m] = (unsigned char)c;
  }
  const float* xb = x + (size_t)b * NTOK * XROW + h * HD;
  for (int pass = 0; pass < 2; ++pass) {
    int e4 = pass * 256 + tid;
    int row = e4 >> 4, col4 = e4 & 15;
    int n_g = n0 + row;
    float4 v = make_float4(0.f, 0.f, 0.f, 0.f);
    if (n_g < NTOK) v = *(const float4*)(xb + (size_t)n_g * XROW + col4 * 4);
    unsigned short* dst = &sm.q_s[row][col4 * 4];
    dst[0] = f2bf(v.x * qscale); dst[1] = f2bf(v.y * qscale);
    dst[2] = f2bf(v.z * qscale); dst[3] = f2bf(v.w * qscale);
  }
  for (int e4 = tid; e4 < 1024; e4 += 256) {
    int tb = e4 >> 9, r2 = e4 & 511, row = r2 >> 4, col4 = r2 & 15;
    const float* src = tb ? tkh : tkv;
    float4 v = make_float4(0.f, 0.f, 0.f, 0.f);
    if (row < 30) v = *(const float4*)(src + row * 64 + col4 * 4);
    unsigned short* dst = &sm.u.pro.tk_s[tb][row][col4 * 4];
    dst[0] = f2bf(v.x * inv_w); dst[1] = f2bf(v.y * inv_w);
    dst[2] = f2bf(v.z * inv_w); dst[3] = f2bf(v.w * inv_w);
  }
  __syncthreads();

  // ---- qv = q_hat . rel_k_table^T (wave -> table tb_w, row group rg) ----
  for (int tt = 0; tt < 2; ++tt) {
    f32x4_t acc = {0.f, 0.f, 0.f, 0.f};
    for (int kk = 0; kk < 2; ++kk) {
      bf16x8_t a = *(const bf16x8_t*)&sm.q_s[rg * 16 + l15][kk * 32 + quad * 8];
      bf16x8_t bb = *(const bf16x8_t*)&sm.u.pro.tk_s[tb_w][tt * 16 + l15][kk * 32 + quad * 8];
      acc = __builtin_amdgcn_mfma_f32_16x16x32_bf16(a, bb, acc, 0, 0, 0);
    }
    for (int r = 0; r < 4; ++r)
      sm.u.pro.qv_t[tb_w][rg * 16 + quad * 4 + r][tt * 16 + l15] = acc[r];
  }
  __syncthreads();

  // ---- pre-scatter: qg[tb][n][g] = qv[tb][n][t(n,g)] (all clamps happen here, once) ----
  for (int p = tid; p < 2 * 32 * 26; p += 256) {
    int tb = p / 832, r2 = p % 832, n = r2 / 26, g = r2 % 26;
    int n_g = n0 + n;
    int t;
    if (n_g == 0 || n_g >= NTOK || g >= 24) t = 0;
    else {
      int base = tb ? ((n_g - 1) % 24) : ((n_g - 1) / 24);
      int dq = g - base; dq = dq < -14 ? -14 : (dq > 14 ? 14 : dq);
      t = dq + 15;
    }
    sm.qg_s[tb][n][g] = sm.u.pro.qv_t[tb][n][t];
  }

  f32x4_t oacc[2] = {{0.f,0.f,0.f,0.f},{0.f,0.f,0.f,0.f}};
  f32x4_t rsacc[2] = {{0.f,0.f,0.f,0.f},{0.f,0.f,0.f,0.f}};
  const float* xk = xb + 768;
  const float* xv = xb + 1536;

  // ---- main K loop over m tiles ----
  for (int step = 0; step < NSTEP; ++step) {
    const int m0 = step * 32;
    __syncthreads();  // prev iter's reads (and prologue qg reads of pro-union) done
    for (int pass = 0; pass < 2; ++pass) {
      int e4 = pass * 256 + tid;
      int row = e4 >> 4, col4 = e4 & 15;
      int m_g = m0 + row;
      float4 kv = make_float4(0.f,0.f,0.f,0.f), vv = make_float4(0.f,0.f,0.f,0.f);
      if (m_g < NTOK) {
        kv = *(const float4*)(xk + (size_t)m_g * XROW + col4 * 4);
        vv = *(const float4*)(xv + (size_t)m_g * XROW + col4 * 4);
      }
      unsigned short* kd = &sm.u.loop.k_s[row][col4 * 4];
      kd[0] = f2bf(kv.x); kd[1] = f2bf(kv.y);
      kd[2] = f2bf(kv.z); kd[3] = f2bf(kv.w);
      int d0 = col4 * 4;
      sm.u.loop.v_sT[d0 + 0][row] = f2bf(vv.x);
      sm.u.loop.v_sT[d0 + 1][row] = f2bf(vv.y);
      sm.u.loop.v_sT[d0 + 2][row] = f2bf(vv.z);
      sm.u.loop.v_sT[d0 + 3][row] = f2bf(vv.w);
    }
    __syncthreads();  // staging visible
    // S = q_hat . k^T  (16x16 per wave)
    f32x4_t s = {0.f, 0.f, 0.f, 0.f};
    for (int kk = 0; kk < 2; ++kk) {
      bf16x8_t a = *(const bf16x8_t*)&sm.q_s[rg * 16 + l15][kk * 32 + quad * 8];
      bf16x8_t bb = *(const bf16x8_t*)&sm.u.loop.k_s[cg * 16 + l15][kk * 32 + quad * 8];
      s = __builtin_amdgcn_mfma_f32_16x16x32_bf16(a, bb, s, 0, 0, 0);
    }
    // rel bias (table lookup by group byte) + exp -> P_s
    const int m_loc = cg * 16 + l15;
    const int m_g = m0 + m_loc;
    const int rmv = sm.rm_s[m_g], cmv = sm.cm_s[m_g];
    const int mpad = (m_g >= NTOK);
    for (int r = 0; r < 4; ++r) {
      int n_loc = rg * 16 + quad * 4 + r;
      float logit = s[r] + sm.qg_s[0][n_loc][rmv] + sm.qg_s[1][n_loc][cmv];
      float p = __expf(logit);
      if (mpad) p = 0.f;
      sm.u.loop.P_s[n_loc][m_loc] = f2bf(p);
    }
    __syncthreads();  // P_s visible
    // O += P.V ; rowsum += P.G
    bf16x8_t a = *(const bf16x8_t*)&sm.u.loop.P_s[rg * 16 + l15][quad * 8];
    for (int sub = 0; sub < 2; ++sub) {
      const unsigned short* vp = &sm.u.loop.v_sT[cg * 32 + sub * 16 + l15][quad * 8];
      bf16x4_t b0 = *(const bf16x4_t*)vp;
      bf16x4_t b1 = *(const bf16x4_t*)(vp + 4);
      bf16x8_t bb;
#pragma unroll
      for (int j = 0; j < 4; ++j) { bb[j] = b0[j]; bb[4 + j] = b1[j]; }
      oacc[sub] = __builtin_amdgcn_mfma_f32_16x16x32_bf16(a, bb, oacc[sub], 0, 0, 0);
    }
    const unsigned char* gsrc = tb_w ? sm.cm_s : sm.rm_s;
    unsigned gw0 = *(const unsigned*)(gsrc + m0 + quad * 8);
    unsigned gw1 = *(const unsigned*)(gsrc + m0 + quad * 8 + 4);
    for (int gt = 0; gt < 2; ++gt) {
      const unsigned g = (unsigned)(gt * 16 + l15);
      bf16x8_t gb;
#pragma unroll
      for (int j = 0; j < 8; ++j) {
        unsigned byte = (j < 4) ? ((gw0 >> (8 * j)) & 255u) : ((gw1 >> (8 * (j - 4))) & 255u);
        gb[j] = (short)((byte == g) ? 0x3F80 : 0);  // bf16 1.0f
      }
      rsacc[gt] = __builtin_amdgcn_mfma_f32_16x16x32_bf16(a, gb, rsacc[gt], 0, 0, 0);
    }
  }

  // ---- epilogue ----
  __syncthreads();  // loop reads done; union switches to epi
  for (int e = tid; e < 2 * 32 * 30; e += 256)
    (&sm.u.epi.sv_f[0][0][0])[e] = 0.f;
  for (int e = tid; e < 4096; e += 256) {
    int t = e & 31, d = (e >> 5) & 63, tb = e >> 11;
    const float* src = tb ? tvh : tvv;
    sm.u.epi.tvT_s[tb][d][t] = (t < 30) ? f2bf(src[t * 64 + d]) : (unsigned short)0;
  }
  __syncthreads();
  // scatter rowsums directly into table-index space (LDS atomics)
  {
    int n_loc4 = rg * 16 + quad * 4;
    for (int gt = 0; gt < 2; ++gt) {
      int g = gt * 16 + l15;
      if (g < 25) {
        for (int r = 0; r < 4; ++r) {
          int n_g = n0 + n_loc4 + r;
          int t;
          if (n_g == 0 || n_g >= NTOK || g == 24) t = 0;
          else {
            int base = tb_w ? ((n_g - 1) % 24) : ((n_g - 1) / 24);
            int dq = g - base; dq = dq < -14 ? -14 : (dq > 14 ? 14 : dq);
            t = dq + 15;
          }
          atomicAdd(&sm.u.epi.sv_f[tb_w][n_loc4 + r][t], rsacc[gt][r]);
        }
      }
    }
  }
  __syncthreads();
  // denominators + bf16 convert
  if (tid < 32) {
    float l = 0.f;
    for (int t = 0; t < 30; ++t) l += sm.u.epi.sv_f[0][tid][t];
    sm.l_s[tid] = l;
  }
  for (int e = tid; e < 2048; e += 256) {
    int tb = e >> 10, r2 = e & 1023, n = r2 >> 5, t = r2 & 31;
    sm.u.epi.sv_bf[tb][n][t] = (t < 30) ? f2bf(sm.u.epi.sv_f[tb][n][t]) : (unsigned short)0;
  }
  for (int sub = 0; sub < 2; ++sub)
    for (int r = 0; r < 4; ++r) oacc[sub][r] *= w;  // scale P.V part only
  __syncthreads();
  // O += sv . tvv^T + sh . tvh^T
  for (int tb = 0; tb < 2; ++tb) {
    bf16x8_t a = *(const bf16x8_t*)&sm.u.epi.sv_bf[tb][rg * 16 + l15][quad * 8];
    for (int sub = 0; sub < 2; ++sub) {
      bf16x8_t bb = *(const bf16x8_t*)&sm.u.epi.tvT_s[tb][cg * 32 + sub * 16 + l15][quad * 8];
      oacc[sub] = __builtin_amdgcn_mfma_f32_16x16x32_bf16(a, bb, oacc[sub], 0, 0, 0);
    }
  }
  // normalize + store
  float* ob = out + (size_t)b * NTOK * (NHEAD * HD) + h * HD;
  for (int r = 0; r < 4; ++r) {
    int n_loc = rg * 16 + quad * 4 + r;
    int n_g = n0 + n_loc;
    if (n_g < NTOK) {
      float inv = 1.f / sm.l_s[n_loc];
      for (int sub = 0; sub < 2; ++sub) {
        int d = cg * 32 + sub * 16 + l15;
        ob[(size_t)n_g * (NHEAD * HD) + d] = oacc[sub][r] * inv;
      }
    }
  }
}

extern "C" void kernel_launch(void* const* d_in, const int* in_sizes, int n_in,
                              void* d_out, int out_size, void* d_ws, size_t ws_size,
                              hipStream_t stream) {
  const float* x   = (const float*)d_in[0];
  const float* wts = (const float*)d_in[1];
  const float* tkv = (const float*)d_in[2];
  const float* tkh = (const float*)d_in[3];
  const float* tvv = (const float*)d_in[4];
  const float* tvh = (const float*)d_in[5];
  float* out = (float*)d_out;
  const int B = in_sizes[0] / (NTOK * XROW);
  dim3 grid(NSTEP, NHEAD, B);  // 19 row-tiles x 12 heads x B
  hma_kernel<<<grid, 256, 0, stream>>>(x, wts, tkv, tkh, tvv, tvh, out);
}

// Round 4
// 294.972 us; speedup vs baseline: 1.2969x; 1.1242x over previous
//
#include <hip/hip_runtime.h>

typedef short bf16x8_t __attribute__((ext_vector_type(8)));
typedef float f32x4_t __attribute__((ext_vector_type(4)));

#define NTOK 577
#define NPAD 608
#define VPAD 640
#define NSTEP 19

__device__ __forceinline__ unsigned short f2bf(float f) {  // RNE (prepass only)
  unsigned u = __builtin_bit_cast(unsigned, f);
  u += 0x7FFFu + ((u >> 16) & 1u);
  return (unsigned short)(u >> 16);
}
__device__ __forceinline__ float headw(const float* wts, int h) {
  float w0 = wts[0], w1 = wts[1], w2 = wts[2];
  return (h < 8) ? (w0 + w1 + w2) : ((h < 10) ? (w1 + w2) : w2);
}
__device__ __forceinline__ unsigned rangemask(int lo, int hi) {
  lo = lo < 0 ? 0 : lo; hi = hi > 32 ? 32 : hi;
  if (hi <= lo) return 0u;
  unsigned mh = (hi >= 32) ? 0xFFFFFFFFu : ((1u << hi) - 1u);
  unsigned ml = (1u << lo) - 1u;  // lo<32 guaranteed here
  return mh & ~ml;
}

// ---------------- prepass: q/k fp32 -> bf16 (q scaled w^2/8), padded to 608 rows ----------------
extern "C" __global__ __launch_bounds__(256) void prep_qk(
    const float* __restrict__ x, const float* __restrict__ wts,
    unsigned short* __restrict__ qbf, unsigned short* __restrict__ kbf) {
  int tid = threadIdx.x;
  int cid = blockIdx.x * 256 + tid;       // 0..9727 = 608 rows x 16 chunks
  int d4 = cid & 15, n = cid >> 4;
  int h = blockIdx.y >> 1, sel = blockIdx.y & 1;
  int b = blockIdx.z;
  float w = headw(wts, h);
  float scale = sel ? 1.f : (w * w * 0.125f);
  float4 v = make_float4(0.f, 0.f, 0.f, 0.f);
  if (n < NTOK) v = *(const float4*)(x + ((size_t)(b * NTOK + n)) * 2304 + sel * 768 + h * 64 + d4 * 4);
  ushort4 o;
  o.x = f2bf(v.x * scale); o.y = f2bf(v.y * scale);
  o.z = f2bf(v.z * scale); o.w = f2bf(v.w * scale);
  unsigned short* base = sel ? kbf : qbf;
  *(ushort4*)(base + (((size_t)(b * 12 + h)) * NPAD + n) * 64 + d4 * 4) = o;
}

// ---------------- prepass: v fp32 -> bf16 transposed [b][h][64][640] ----------------
extern "C" __global__ __launch_bounds__(256) void prep_v(
    const float* __restrict__ x, unsigned short* __restrict__ vbf) {
  __shared__ unsigned short t_s[64][72];
  int tid = threadIdx.x;
  int n0 = blockIdx.x * 64, h = blockIdx.y, b = blockIdx.z;
  for (int p = 0; p < 4; ++p) {
    int c = p * 256 + tid;
    int ni = c >> 4, d4 = c & 15;
    int n = n0 + ni;
    float4 v = make_float4(0.f, 0.f, 0.f, 0.f);
    if (n < NTOK) v = *(const float4*)(x + ((size_t)(b * NTOK + n)) * 2304 + 1536 + h * 64 + d4 * 4);
    t_s[d4 * 4 + 0][ni] = f2bf(v.x);
    t_s[d4 * 4 + 1][ni] = f2bf(v.y);
    t_s[d4 * 4 + 2][ni] = f2bf(v.z);
    t_s[d4 * 4 + 3][ni] = f2bf(v.w);
  }
  __syncthreads();
  for (int p = 0; p < 2; ++p) {
    int c = p * 256 + tid;
    int d = c >> 3, n8 = c & 7;
    bf16x8_t val = *(const bf16x8_t*)&t_s[d][n8 * 8];
    *(bf16x8_t*)(vbf + ((size_t)(b * 12 + h) * 64 + d) * VPAD + n0 + n8 * 8) = val;
  }
}

// ---------------- prepass: tables. tkb[h][tb][32][64] (x 1/w), tvb[tb][64][32] transposed ----------------
extern "C" __global__ __launch_bounds__(256) void prep_tab(
    const float* __restrict__ wts,
    const float* __restrict__ tkv, const float* __restrict__ tkh,
    const float* __restrict__ tvv, const float* __restrict__ tvh,
    unsigned short* __restrict__ tkb, unsigned short* __restrict__ tvb) {
  int tid = threadIdx.x, bx = blockIdx.x;
  if (bx < 48) {
    int cid = bx * 256 + tid;             // 12*2*32*16 = 12288
    int d4 = cid & 15, t = (cid >> 4) & 31, tb = (cid >> 9) & 1, h = cid >> 10;
    float s = 1.f / headw(wts, h);
    const float* src = tb ? tkh : tkv;
    float4 v = make_float4(0.f, 0.f, 0.f, 0.f);
    if (t < 30) v = *(const float4*)(src + t * 64 + d4 * 4);
    ushort4 o;
    o.x = f2bf(v.x * s); o.y = f2bf(v.y * s); o.z = f2bf(v.z * s); o.w = f2bf(v.w * s);
    *(ushort4*)(tkb + (((size_t)(h * 2 + tb)) * 32 + t) * 64 + d4 * 4) = o;
  } else {
    for (int i = 0; i < 16; ++i) {
      int id = tid * 16 + i;              // 4096 = 2*64*32, t fastest
      int t = id & 31, d = (id >> 5) & 63, tb = id >> 11;
      const float* src = tb ? tvh : tvv;
      tvb[id] = (t < 30) ? f2bf(src[t * 64 + d]) : (unsigned short)0;
    }
  }
}

// ---------------- main kernel ----------------
struct __align__(16) SMem {
  unsigned short q_s[32][72];          // 4608 B
  float qg_s[2][32][25];               // 6400 B  (pre-scattered rel-k bias by group)
  unsigned gmask_s[2][NSTEP][25];      // 3800 B  (bit m_loc: grp(m0+m_loc)==g)
  union {                              // 12288 B
    struct { float qv_t[2][32][32]; } pro;
    struct {
      unsigned short k_s[32][72];
      unsigned short v_sT[64][40];
      unsigned short P_s[32][40];
    } loop;
    struct {
      float sv_f[2][32][30];
      unsigned short sv_bf[2][32][32];
      float l_s[32];
    } epi;
  } u;
};  // ~27104 B -> 6 blocks/CU

extern "C" __global__ __launch_bounds__(256, 6) void hma_kernel(
    const unsigned short* __restrict__ qbf, const unsigned short* __restrict__ kbf,
    const unsigned short* __restrict__ vbf, const unsigned short* __restrict__ tkb,
    const unsigned short* __restrict__ tvb, const float* __restrict__ wts,
    float* __restrict__ out) {
  __shared__ SMem sm;
  const int tid = threadIdx.x;
  const int wave = tid >> 6, lane = tid & 63, quad = lane >> 4, l15 = lane & 15;
  const int rg = wave & 1, cg = wave >> 1, tb_w = wave >> 1;
  const int n0 = blockIdx.x * 32;
  const int h = blockIdx.y, b = blockIdx.z;
  const float w = headw(wts, h);

  const unsigned short* qb = qbf + ((size_t)(b * 12 + h)) * NPAD * 64;
  const unsigned short* kb = kbf + ((size_t)(b * 12 + h)) * NPAD * 64;
  const unsigned short* vb = vbf + ((size_t)(b * 12 + h)) * 64 * VPAD;

  // stage q (bf16, pre-scaled)
  {
    int row = tid >> 3, ch = tid & 7;
    bf16x8_t v = *(const bf16x8_t*)(qb + (size_t)(n0 + row) * 64 + ch * 8);
    *(bf16x8_t*)&sm.q_s[row][ch * 8] = v;
  }
  // gmask build (no dependence on q)
  for (int p = tid; p < 2 * NSTEP * 25; p += 256) {
    int tb = p / (NSTEP * 25), r2 = p % (NSTEP * 25), step = r2 / 25, g = r2 % 25;
    int m0 = step * 32;
    unsigned mask;
    if (g == 24) {
      mask = rangemask(NTOK - m0, NPAD - m0);     // pad tokens
      if (step == 0) mask |= 1u;                  // CLS
    } else if (tb == 0) {
      mask = rangemask(24 * g + 1 - m0, 24 * g + 25 - m0);
    } else {
      mask = 0u;
      int j0 = (g + 1 - m0) % 24; if (j0 < 0) j0 += 24;
      for (int j = j0; j < 32; j += 24) {
        int m = m0 + j;
        if (m >= 1 && m < NTOK) mask |= (1u << j);
      }
    }
    sm.gmask_s[tb][step][g] = mask;
  }
  __syncthreads();
  // qv = q_hat . tk^T, B-fragments straight from global (L2-resident)
  {
    const unsigned short* tkp = tkb + ((size_t)(h * 2 + tb_w)) * 32 * 64;
    for (int tt = 0; tt < 2; ++tt) {
      f32x4_t acc = {0.f, 0.f, 0.f, 0.f};
      for (int kk = 0; kk < 2; ++kk) {
        bf16x8_t a = *(const bf16x8_t*)&sm.q_s[rg * 16 + l15][kk * 32 + quad * 8];
        bf16x8_t bb = *(const bf16x8_t*)(tkp + (size_t)(tt * 16 + l15) * 64 + kk * 32 + quad * 8);
        acc = __builtin_amdgcn_mfma_f32_16x16x32_bf16(a, bb, acc, 0, 0, 0);
      }
      for (int r = 0; r < 4; ++r)
        sm.u.pro.qv_t[tb_w][rg * 16 + quad * 4 + r][tt * 16 + l15] = acc[r];
    }
  }
  __syncthreads();
  // pre-scatter rel-k bias by group
  for (int p = tid; p < 2 * 32 * 25; p += 256) {
    int tb = p / 800, r2 = p % 800, n = r2 / 25, g = r2 % 25;
    int n_g = n0 + n;
    int t;
    if (n_g == 0 || n_g >= NTOK || g == 24) t = 0;
    else {
      int base = tb ? ((n_g - 1) % 24) : ((n_g - 1) / 24);
      int dq = g - base; dq = dq < -14 ? -14 : (dq > 14 ? 14 : dq);
      t = dq + 15;
    }
    sm.qg_s[tb][n][g] = sm.u.pro.qv_t[tb][n][t];
  }

  // per-thread m-group trackers (incremental, no div in loop)
  const int m_loc = cg * 16 + l15;
  int rmv, cmv;
  if (m_loc == 0) { rmv = 0; cmv = -1; }
  else { rmv = (m_loc - 1) / 24; cmv = (m_loc - 1) - rmv * 24; }
  const bool cls_lane = (m_loc == 0);

  f32x4_t oacc[2] = {{0,0,0,0},{0,0,0,0}};
  f32x4_t rsacc[2] = {{0,0,0,0},{0,0,0,0}};

  // staging prefetch (step 0)
  const int krow = tid >> 3, kch = tid & 7;
  const int vrow = tid >> 2, vch = tid & 3;
  const unsigned short* kptr = kb + (size_t)krow * 64 + kch * 8;
  const unsigned short* vptr = vb + (size_t)vrow * VPAD + vch * 8;
  bf16x8_t kreg = *(const bf16x8_t*)kptr;
  bf16x8_t vreg = *(const bf16x8_t*)vptr;

  for (int step = 0; step < NSTEP; ++step) {
    const int m0 = step * 32;
    __syncthreads();                         // prev-step LDS reads done (also covers qg/qv_t)
    *(bf16x8_t*)&sm.u.loop.k_s[krow][kch * 8] = kreg;
    *(bf16x8_t*)&sm.u.loop.v_sT[vrow][vch * 8] = vreg;
    __syncthreads();                         // staging visible
    if (step < NSTEP - 1) {                  // prefetch next step during compute
      kreg = *(const bf16x8_t*)(kptr + (size_t)(m0 + 32) * 64);
      vreg = *(const bf16x8_t*)(vptr + (m0 + 32));
    }
    // S = q_hat . k^T
    f32x4_t s = {0.f, 0.f, 0.f, 0.f};
    for (int kk = 0; kk < 2; ++kk) {
      bf16x8_t a = *(const bf16x8_t*)&sm.q_s[rg * 16 + l15][kk * 32 + quad * 8];
      bf16x8_t bb = *(const bf16x8_t*)&sm.u.loop.k_s[cg * 16 + l15][kk * 32 + quad * 8];
      s = __builtin_amdgcn_mfma_f32_16x16x32_bf16(a, bb, s, 0, 0, 0);
    }
    // rel bias + exp -> P
    const int m_g = m0 + m_loc;
    int ur = rmv, uc = cmv;
    if (cls_lane && step == 0) { ur = 24; uc = 24; }
    const bool mpad = (m_g >= NTOK);         // garbage ur index stays in-struct; p zeroed below
    for (int r = 0; r < 4; ++r) {
      int n_loc = rg * 16 + quad * 4 + r;
      float logit = s[r] + sm.qg_s[0][n_loc][ur] + sm.qg_s[1][n_loc][uc];
      float p = __expf(logit);
      if (mpad) p = 0.f;
      unsigned u = __builtin_bit_cast(unsigned, p);
      sm.u.loop.P_s[n_loc][m_loc] = (unsigned short)((u + 0x8000u) >> 16);  // round-half-up
    }
    { int c = cmv + 8; int carry = (c >= 24); cmv = carry ? c - 24 : c; rmv += 1 + carry; }
    __syncthreads();                         // P visible
    // O += P.V
    bf16x8_t a = *(const bf16x8_t*)&sm.u.loop.P_s[rg * 16 + l15][quad * 8];
    for (int sub = 0; sub < 2; ++sub) {
      bf16x8_t bb = *(const bf16x8_t*)&sm.u.loop.v_sT[cg * 32 + sub * 16 + l15][quad * 8];
      oacc[sub] = __builtin_amdgcn_mfma_f32_16x16x32_bf16(a, bb, oacc[sub], 0, 0, 0);
    }
    // rowsum += P.G via precomputed masks + bit-spread
    // gb[j] must equal bit (quad*8+j) of mask. y0/y1 place bits b0..b3 / b4..b7
    // at byte LSBs; mask each byte-PAIR before combining (R3 bug: OR without
    // masking leaked b2 into gb[1] etc., double-counting run boundaries).
    for (int gt = 0; gt < 2; ++gt) {
      unsigned g = (unsigned)(gt * 16 + l15);
      unsigned mask = (g < 25) ? sm.gmask_s[tb_w][step][g] : 0u;
      unsigned bits = (mask >> (quad * 8)) & 0xFFu;
      unsigned y0 = ((bits & 0xFu) * 0x204081u) & 0x01010101u;  // b0..b3 -> bits 0,8,16,24
      unsigned y1 = ((bits >> 4) * 0x204081u) & 0x01010101u;    // b4..b7
      unsigned p01 = y0 & 0x0101u, p23 = (y0 >> 16) & 0x0101u;
      unsigned p45 = y1 & 0x0101u, p67 = (y1 >> 16) & 0x0101u;
      union { unsigned uu[4]; bf16x8_t v; } gbu;
      gbu.uu[0] = ((p01 | (p01 << 8)) & 0x00010001u) * 0x3F80u;
      gbu.uu[1] = ((p23 | (p23 << 8)) & 0x00010001u) * 0x3F80u;
      gbu.uu[2] = ((p45 | (p45 << 8)) & 0x00010001u) * 0x3F80u;
      gbu.uu[3] = ((p67 | (p67 << 8)) & 0x00010001u) * 0x3F80u;
      rsacc[gt] = __builtin_amdgcn_mfma_f32_16x16x32_bf16(a, gbu.v, rsacc[gt], 0, 0, 0);
    }
  }

  // ---- epilogue ----
  __syncthreads();
  for (int e = tid; e < 2 * 32 * 30; e += 256) (&sm.u.epi.sv_f[0][0][0])[e] = 0.f;
  __syncthreads();
  {
    int n_loc4 = rg * 16 + quad * 4;
    for (int gt = 0; gt < 2; ++gt) {
      int g = gt * 16 + l15;
      if (g < 25) {
        for (int r = 0; r < 4; ++r) {
          int n_g = n0 + n_loc4 + r;
          int t;
          if (n_g == 0 || n_g >= NTOK || g == 24) t = 0;
          else {
            int base = tb_w ? ((n_g - 1) % 24) : ((n_g - 1) / 24);
            int dq = g - base; dq = dq < -14 ? -14 : (dq > 14 ? 14 : dq);
            t = dq + 15;
          }
          atomicAdd(&sm.u.epi.sv_f[tb_w][n_loc4 + r][t], rsacc[gt][r]);
        }
      }
    }
  }
  __syncthreads();
  if (tid < 32) {
    float l = 0.f;
    for (int t = 0; t < 30; ++t) l += sm.u.epi.sv_f[0][tid][t];
    sm.u.epi.l_s[tid] = l;
  }
  for (int e = tid; e < 2048; e += 256) {
    int tb = e >> 10, r2 = e & 1023, n = r2 >> 5, t = r2 & 31;
    float v = (t < 30) ? sm.u.epi.sv_f[tb][n][t] : 0.f;
    unsigned u = __builtin_bit_cast(unsigned, v);
    sm.u.epi.sv_bf[tb][n][t] = (unsigned short)((u + 0x8000u) >> 16);
  }
  for (int sub = 0; sub < 2; ++sub)
    for (int r = 0; r < 4; ++r) oacc[sub][r] *= w;   // scale P.V part only
  __syncthreads();
  // O += sv . tv^T, B-fragments from global
  for (int tb = 0; tb < 2; ++tb) {
    bf16x8_t a = *(const bf16x8_t*)&sm.u.epi.sv_bf[tb][rg * 16 + l15][quad * 8];
    for (int sub = 0; sub < 2; ++sub) {
      bf16x8_t bb = *(const bf16x8_t*)(tvb + ((size_t)(tb * 64 + cg * 32 + sub * 16 + l15)) * 32 + quad * 8);
      oacc[sub] = __builtin_amdgcn_mfma_f32_16x16x32_bf16(a, bb, oacc[sub], 0, 0, 0);
    }
  }
  // normalize + store
  float* ob = out + (size_t)b * NTOK * 768 + h * 64;
  for (int r = 0; r < 4; ++r) {
    int n_loc = rg * 16 + quad * 4 + r;
    int n_g = n0 + n_loc;
    if (n_g < NTOK) {
      float inv = 1.f / sm.u.epi.l_s[n_loc];
      for (int sub = 0; sub < 2; ++sub) {
        int d = cg * 32 + sub * 16 + l15;
        ob[(size_t)n_g * 768 + d] = oacc[sub][r] * inv;
      }
    }
  }
}

extern "C" void kernel_launch(void* const* d_in, const int* in_sizes, int n_in,
                              void* d_out, int out_size, void* d_ws, size_t ws_size,
                              hipStream_t stream) {
  const float* x   = (const float*)d_in[0];
  const float* wts = (const float*)d_in[1];
  const float* tkv = (const float*)d_in[2];
  const float* tkh = (const float*)d_in[3];
  const float* tvv = (const float*)d_in[4];
  const float* tvh = (const float*)d_in[5];
  float* out = (float*)d_out;
  const int B = in_sizes[0] / (NTOK * 2304);

  unsigned short* ws = (unsigned short*)d_ws;
  size_t qkSz = (size_t)B * 12 * NPAD * 64;
  size_t vSz  = (size_t)B * 12 * 64 * VPAD;
  unsigned short* qbf = ws;
  unsigned short* kbf = ws + qkSz;
  unsigned short* vbf = ws + 2 * qkSz;
  unsigned short* tkb = vbf + vSz;
  unsigned short* tvb = tkb + (size_t)12 * 2 * 32 * 64;

  prep_qk<<<dim3(38, 24, B), 256, 0, stream>>>(x, wts, qbf, kbf);
  prep_v<<<dim3(10, 12, B), 256, 0, stream>>>(x, vbf);
  prep_tab<<<dim3(49, 1, 1), 256, 0, stream>>>(wts, tkv, tkh, tvv, tvh, tkb, tvb);
  hma_kernel<<<dim3(NSTEP, 12, B), 256, 0, stream>>>(qbf, kbf, vbf, tkb, tvb, wts, out);
}

// Round 5
// 274.907 us; speedup vs baseline: 1.3916x; 1.0730x over previous
//
#include <hip/hip_runtime.h>

typedef short bf16x8_t __attribute__((ext_vector_type(8)));
typedef float f32x4_t __attribute__((ext_vector_type(4)));

#define NTOK 577
#define QPAD 640   // q/k row padding (n up to 639 for 64-row tiles; k rows 608..639 zero)
#define MPAD 608   // m range actually iterated (19*32)
#define NSTEP 19

__device__ __forceinline__ unsigned short f2bf(float f) {  // RNE (prepass only)
  unsigned u = __builtin_bit_cast(unsigned, f);
  u += 0x7FFFu + ((u >> 16) & 1u);
  return (unsigned short)(u >> 16);
}
__device__ __forceinline__ float headw(const float* wts, int h) {
  float w0 = wts[0], w1 = wts[1], w2 = wts[2];
  return (h < 8) ? (w0 + w1 + w2) : ((h < 10) ? (w1 + w2) : w2);
}
__device__ __forceinline__ unsigned rangemask(int lo, int hi) {
  lo = lo < 0 ? 0 : lo; hi = hi > 32 ? 32 : hi;
  if (hi <= lo) return 0u;
  unsigned mh = (hi >= 32) ? 0xFFFFFFFFu : ((1u << hi) - 1u);
  unsigned ml = (1u << lo) - 1u;
  return mh & ~ml;
}

// ---------------- prepass: one pass over x -> q*(w^2/8), k, v^T (all bf16) ----------------
extern "C" __global__ __launch_bounds__(256) void prep_x(
    const float* __restrict__ x, const float* __restrict__ wts,
    unsigned short* __restrict__ qbf, unsigned short* __restrict__ kbf,
    unsigned short* __restrict__ vbf) {
  __shared__ unsigned short t_s[64][72];
  const int tid = threadIdx.x;
  const int n0 = blockIdx.x * 64, h = blockIdx.y, b = blockIdx.z;
  const float w = headw(wts, h);
  const float qs = w * w * 0.125f;
  const float* xb = x + (size_t)(b * NTOK) * 2304 + h * 64;
  unsigned short* qo = qbf + ((size_t)(b * 12 + h)) * QPAD * 64;
  unsigned short* ko = kbf + ((size_t)(b * 12 + h)) * QPAD * 64;
  for (int p = 0; p < 4; ++p) {
    int idx = p * 256 + tid;
    int row = idx >> 4, c4 = idx & 15;
    int n = n0 + row;
    float4 vq = {0,0,0,0}, vk = {0,0,0,0}, vv = {0,0,0,0};
    if (n < NTOK) {
      const float* rp = xb + (size_t)n * 2304 + c4 * 4;
      vq = *(const float4*)rp;
      vk = *(const float4*)(rp + 768);
      vv = *(const float4*)(rp + 1536);
    }
    ushort4 oq, ok;
    oq.x = f2bf(vq.x * qs); oq.y = f2bf(vq.y * qs); oq.z = f2bf(vq.z * qs); oq.w = f2bf(vq.w * qs);
    ok.x = f2bf(vk.x); ok.y = f2bf(vk.y); ok.z = f2bf(vk.z); ok.w = f2bf(vk.w);
    *(ushort4*)(qo + (size_t)(n0 + row) * 64 + c4 * 4) = oq;
    *(ushort4*)(ko + (size_t)(n0 + row) * 64 + c4 * 4) = ok;
    t_s[c4 * 4 + 0][row] = f2bf(vv.x);
    t_s[c4 * 4 + 1][row] = f2bf(vv.y);
    t_s[c4 * 4 + 2][row] = f2bf(vv.z);
    t_s[c4 * 4 + 3][row] = f2bf(vv.w);
  }
  __syncthreads();
  for (int p = 0; p < 2; ++p) {
    int c = p * 256 + tid;
    int d = c >> 3, n8 = c & 7;
    bf16x8_t val = *(const bf16x8_t*)&t_s[d][n8 * 8];
    *(bf16x8_t*)(vbf + ((size_t)(b * 12 + h) * 64 + d) * QPAD + n0 + n8 * 8) = val;
  }
}

// ---------------- prepass: tables. tkb[h][tb][32][64] (x 1/w), tvb[tb][64][32] transposed ----------------
extern "C" __global__ __launch_bounds__(256) void prep_tab(
    const float* __restrict__ wts,
    const float* __restrict__ tkv, const float* __restrict__ tkh,
    const float* __restrict__ tvv, const float* __restrict__ tvh,
    unsigned short* __restrict__ tkb, unsigned short* __restrict__ tvb) {
  int tid = threadIdx.x, bx = blockIdx.x;
  if (bx < 48) {
    int cid = bx * 256 + tid;
    int d4 = cid & 15, t = (cid >> 4) & 31, tb = (cid >> 9) & 1, h = cid >> 10;
    float s = 1.f / headw(wts, h);
    const float* src = tb ? tkh : tkv;
    float4 v = {0,0,0,0};
    if (t < 30) v = *(const float4*)(src + t * 64 + d4 * 4);
    ushort4 o;
    o.x = f2bf(v.x * s); o.y = f2bf(v.y * s); o.z = f2bf(v.z * s); o.w = f2bf(v.w * s);
    *(ushort4*)(tkb + (((size_t)(h * 2 + tb)) * 32 + t) * 64 + d4 * 4) = o;
  } else {
    for (int i = 0; i < 16; ++i) {
      int id = tid * 16 + i;              // 4096 = 2*64*32, t fastest
      int t = id & 31, d = (id >> 5) & 63, tb = id >> 11;
      const float* src = tb ? tvh : tvv;
      tvb[id] = (t < 30) ? f2bf(src[t * 64 + d]) : (unsigned short)0;
    }
  }
}

// ---------------- main kernel: 64 n-rows x full m per block ----------------
struct __align__(16) SMem {
  float qg_s[2][64][25];               // 12800 B  pre-scattered rel-k bias by group
  unsigned gmask_s[2][NSTEP][25];      // 3800 B   bit m_loc: grp(m0+m_loc)==g
  float l_s[64];                       // 256 B    softmax denominators
  union {                              // 15360 B
    struct { float qv_t[2][64][30]; } pro;
    struct {
      unsigned short k_s[32][72];      // 4608  (144B rows, 16B-mult)
      unsigned short v_sT[64][40];     // 5120  (80B rows)
      unsigned short P_s[64][40];      // 5120
    } loop;
    struct { float sv_f[2][64][30]; } epi;
  } u;
};  // 32216 B -> 5 blocks/CU

extern "C" __global__ __launch_bounds__(256, 5) void hma_kernel(
    const unsigned short* __restrict__ qbf, const unsigned short* __restrict__ kbf,
    const unsigned short* __restrict__ vbf, const unsigned short* __restrict__ tkb,
    const unsigned short* __restrict__ tvb, const float* __restrict__ wts,
    float* __restrict__ out) {
  __shared__ SMem sm;
  const int tid = threadIdx.x;
  const int wave = tid >> 6, lane = tid & 63, quad = lane >> 4, l15 = lane & 15;
  const int rg = wave & 1;      // n-half (32 rows)
  const int cg = wave >> 1;     // m-half within step / d-half / table id
  const int tb_w = cg;
  const int n0 = blockIdx.x * 64;
  const int h = blockIdx.y, b = blockIdx.z;
  const float w = headw(wts, h);

  const unsigned short* qb = qbf + ((size_t)(b * 12 + h)) * QPAD * 64;
  const unsigned short* kb = kbf + ((size_t)(b * 12 + h)) * QPAD * 64;
  const unsigned short* vb = vbf + ((size_t)(b * 12 + h)) * 64 * QPAD;

  // q fragments: registers only, straight from global (pre-scaled bf16)
  bf16x8_t qa[2][2];
  for (int sub = 0; sub < 2; ++sub)
    for (int kk = 0; kk < 2; ++kk)
      qa[sub][kk] = *(const bf16x8_t*)(qb + (size_t)(n0 + rg * 32 + sub * 16 + l15) * 64 + kk * 32 + quad * 8);

  // gmask build
  for (int p = tid; p < 2 * NSTEP * 25; p += 256) {
    int tb = p / (NSTEP * 25), r2 = p % (NSTEP * 25), step = r2 / 25, g = r2 % 25;
    int m0 = step * 32;
    unsigned mask;
    if (g == 24) {
      mask = rangemask(NTOK - m0, MPAD - m0);
      if (step == 0) mask |= 1u;
    } else if (tb == 0) {
      mask = rangemask(24 * g + 1 - m0, 24 * g + 25 - m0);
    } else {
      mask = 0u;
      int j0 = (g + 1 - m0) % 24; if (j0 < 0) j0 += 24;
      for (int j = j0; j < 32; j += 24) {
        int m = m0 + j;
        if (m >= 1 && m < NTOK) mask |= (1u << j);
      }
    }
    sm.gmask_s[tb][step][g] = mask;
  }

  // qv = q_hat . tk^T  (B-frags from global; each wave: table tb_w, n-half rg)
  {
    const unsigned short* tkp = tkb + ((size_t)(h * 2 + tb_w)) * 32 * 64;
    for (int tt = 0; tt < 2; ++tt) {
      for (int sub = 0; sub < 2; ++sub) {
        f32x4_t acc = {0.f, 0.f, 0.f, 0.f};
        for (int kk = 0; kk < 2; ++kk) {
          bf16x8_t bb = *(const bf16x8_t*)(tkp + (size_t)(tt * 16 + l15) * 64 + kk * 32 + quad * 8);
          acc = __builtin_amdgcn_mfma_f32_16x16x32_bf16(qa[sub][kk], bb, acc, 0, 0, 0);
        }
        int t = tt * 16 + l15;
        if (t < 30)
          for (int r = 0; r < 4; ++r)
            sm.u.pro.qv_t[tb_w][rg * 32 + sub * 16 + quad * 4 + r][t] = acc[r];
      }
    }
  }
  __syncthreads();
  // pre-scatter rel-k bias by group
  for (int p = tid; p < 2 * 64 * 25; p += 256) {
    int tb = p / 1600, r2 = p % 1600, n = r2 / 25, g = r2 % 25;
    int n_g = n0 + n;
    int t;
    if (n_g == 0 || n_g >= NTOK || g == 24) t = 0;
    else {
      int base = tb ? ((n_g - 1) % 24) : ((n_g - 1) / 24);
      int dq = g - base; dq = dq < -14 ? -14 : (dq > 14 ? 14 : dq);
      t = dq + 15;
    }
    sm.qg_s[tb][n][g] = sm.u.pro.qv_t[tb][n][t];
  }

  // per-thread m-group trackers
  const int m_loc = cg * 16 + l15;
  int rmv, cmv;
  if (m_loc == 0) { rmv = 0; cmv = -1; }
  else { rmv = (m_loc - 1) / 24; cmv = (m_loc - 1) - rmv * 24; }
  const bool cls_lane = (m_loc == 0);

  f32x4_t oacc[2][2] = {{{0,0,0,0},{0,0,0,0}},{{0,0,0,0},{0,0,0,0}}};
  f32x4_t rsacc[2][2] = {{{0,0,0,0},{0,0,0,0}},{{0,0,0,0},{0,0,0,0}}};

  const int krow = tid >> 3, kch = tid & 7;
  const int vrow = tid >> 2, vch = tid & 3;
  const unsigned short* kptr = kb + (size_t)krow * 64 + kch * 8;
  const unsigned short* vptr = vb + (size_t)vrow * QPAD + vch * 8;
  bf16x8_t kreg = *(const bf16x8_t*)kptr;
  bf16x8_t vreg = *(const bf16x8_t*)vptr;

  for (int step = 0; step < NSTEP; ++step) {
    const int m0 = step * 32;
    __syncthreads();                          // prev-step reads done (covers qg build too)
    *(bf16x8_t*)&sm.u.loop.k_s[krow][kch * 8] = kreg;
    *(bf16x8_t*)&sm.u.loop.v_sT[vrow][vch * 8] = vreg;
    __syncthreads();
    kreg = *(const bf16x8_t*)(kptr + (size_t)(m0 + 32) * 64);  // rows 608..639 are zero pad
    vreg = *(const bf16x8_t*)(vptr + (m0 + 32));
    // S = q_hat . k^T  (two n-subtiles per wave)
    f32x4_t s[2] = {{0,0,0,0},{0,0,0,0}};
    {
      bf16x8_t kb0 = *(const bf16x8_t*)&sm.u.loop.k_s[cg * 16 + l15][quad * 8];
      bf16x8_t kb1 = *(const bf16x8_t*)&sm.u.loop.k_s[cg * 16 + l15][32 + quad * 8];
      for (int sub = 0; sub < 2; ++sub) {
        s[sub] = __builtin_amdgcn_mfma_f32_16x16x32_bf16(qa[sub][0], kb0, s[sub], 0, 0, 0);
        s[sub] = __builtin_amdgcn_mfma_f32_16x16x32_bf16(qa[sub][1], kb1, s[sub], 0, 0, 0);
      }
    }
    // rel bias + exp -> P
    const int m_g = m0 + m_loc;
    int ur = rmv, uc = cmv;
    if (cls_lane && step == 0) { ur = 24; uc = 24; }
    const bool mpad = (m_g >= NTOK);
    for (int sub = 0; sub < 2; ++sub)
      for (int r = 0; r < 4; ++r) {
        int n_loc = rg * 32 + sub * 16 + quad * 4 + r;
        float logit = s[sub][r] + sm.qg_s[0][n_loc][ur] + sm.qg_s[1][n_loc][uc];
        float p = __expf(logit);
        if (mpad) p = 0.f;
        unsigned u = __builtin_bit_cast(unsigned, p);
        sm.u.loop.P_s[n_loc][m_loc] = (unsigned short)((u + 0x8000u) >> 16);
      }
    { int c = cmv + 8; int carry = (c >= 24); cmv = carry ? c - 24 : c; rmv += 1 + carry; }
    __syncthreads();
    // A fragments (P) shared by PV and G
    bf16x8_t pa[2];
    for (int sub = 0; sub < 2; ++sub)
      pa[sub] = *(const bf16x8_t*)&sm.u.loop.P_s[rg * 32 + sub * 16 + l15][quad * 8];
    // O += P.V
    for (int ds = 0; ds < 2; ++ds) {
      bf16x8_t bb = *(const bf16x8_t*)&sm.u.loop.v_sT[cg * 32 + ds * 16 + l15][quad * 8];
      for (int sub = 0; sub < 2; ++sub)
        oacc[sub][ds] = __builtin_amdgcn_mfma_f32_16x16x32_bf16(pa[sub], bb, oacc[sub][ds], 0, 0, 0);
    }
    // rowsum += P.G  (masks precomputed; byte-pair-masked bit spread — R4-verified)
    for (int gt = 0; gt < 2; ++gt) {
      unsigned g = (unsigned)(gt * 16 + l15);
      unsigned mask = (g < 25) ? sm.gmask_s[tb_w][step][g] : 0u;
      unsigned bits = (mask >> (quad * 8)) & 0xFFu;
      unsigned y0 = ((bits & 0xFu) * 0x204081u) & 0x01010101u;
      unsigned y1 = ((bits >> 4) * 0x204081u) & 0x01010101u;
      unsigned p01 = y0 & 0x0101u, p23 = (y0 >> 16) & 0x0101u;
      unsigned p45 = y1 & 0x0101u, p67 = (y1 >> 16) & 0x0101u;
      union { unsigned uu[4]; bf16x8_t v; } gbu;
      gbu.uu[0] = ((p01 | (p01 << 8)) & 0x00010001u) * 0x3F80u;
      gbu.uu[1] = ((p23 | (p23 << 8)) & 0x00010001u) * 0x3F80u;
      gbu.uu[2] = ((p45 | (p45 << 8)) & 0x00010001u) * 0x3F80u;
      gbu.uu[3] = ((p67 | (p67 << 8)) & 0x00010001u) * 0x3F80u;
      for (int sub = 0; sub < 2; ++sub)
        rsacc[sub][gt] = __builtin_amdgcn_mfma_f32_16x16x32_bf16(pa[sub], gbu.v, rsacc[sub][gt], 0, 0, 0);
    }
  }

  // ---- epilogue ----
  __syncthreads();
  for (int e = tid; e < 2 * 64 * 30; e += 256) (&sm.u.epi.sv_f[0][0][0])[e] = 0.f;
  __syncthreads();
  for (int sub = 0; sub < 2; ++sub)
    for (int gt = 0; gt < 2; ++gt) {
      int g = gt * 16 + l15;
      if (g < 25) {
        for (int r = 0; r < 4; ++r) {
          int n_loc = rg * 32 + sub * 16 + quad * 4 + r;
          int n_g = n0 + n_loc;
          int t;
          if (n_g == 0 || n_g >= NTOK || g == 24) t = 0;
          else {
            int base = tb_w ? ((n_g - 1) % 24) : ((n_g - 1) / 24);
            int dq = g - base; dq = dq < -14 ? -14 : (dq > 14 ? 14 : dq);
            t = dq + 15;
          }
          atomicAdd(&sm.u.epi.sv_f[tb_w][n_loc][t], rsacc[sub][gt][r]);
        }
      }
    }
  __syncthreads();
  if (tid < 64) {
    float l = 0.f;
    for (int t = 0; t < 30; ++t) l += sm.u.epi.sv_f[0][tid][t];
    sm.l_s[tid] = l;
  }
  for (int sub = 0; sub < 2; ++sub)
    for (int ds = 0; ds < 2; ++ds)
      for (int r = 0; r < 4; ++r) oacc[sub][ds][r] *= w;   // scale P.V part only
  // O += sv . tv^T  (A built from sv_f, B from global tvb)
  for (int tb = 0; tb < 2; ++tb) {
    bf16x8_t av[2];
    for (int sub = 0; sub < 2; ++sub) {
      int n_loc = rg * 32 + sub * 16 + l15;
      for (int j = 0; j < 8; ++j) {
        int t = quad * 8 + j;
        float f = (t < 30) ? sm.u.epi.sv_f[tb][n_loc][t] : 0.f;
        unsigned u = __builtin_bit_cast(unsigned, f);
        av[sub][j] = (short)((u + 0x8000u) >> 16);
      }
    }
    for (int ds = 0; ds < 2; ++ds) {
      bf16x8_t bb = *(const bf16x8_t*)(tvb + ((size_t)(tb * 64 + cg * 32 + ds * 16 + l15)) * 32 + quad * 8);
      for (int sub = 0; sub < 2; ++sub)
        oacc[sub][ds] = __builtin_amdgcn_mfma_f32_16x16x32_bf16(av[sub], bb, oacc[sub][ds], 0, 0, 0);
    }
  }
  __syncthreads();   // l_s ready
  // normalize + store
  float* ob = out + (size_t)b * NTOK * 768 + h * 64;
  for (int sub = 0; sub < 2; ++sub)
    for (int r = 0; r < 4; ++r) {
      int n_loc = rg * 32 + sub * 16 + quad * 4 + r;
      int n_g = n0 + n_loc;
      if (n_g < NTOK) {
        float inv = 1.f / sm.l_s[n_loc];
        for (int ds = 0; ds < 2; ++ds) {
          int d = cg * 32 + ds * 16 + l15;
          ob[(size_t)n_g * 768 + d] = oacc[sub][ds][r] * inv;
        }
      }
    }
}

extern "C" void kernel_launch(void* const* d_in, const int* in_sizes, int n_in,
                              void* d_out, int out_size, void* d_ws, size_t ws_size,
                              hipStream_t stream) {
  const float* x   = (const float*)d_in[0];
  const float* wts = (const float*)d_in[1];
  const float* tkv = (const float*)d_in[2];
  const float* tkh = (const float*)d_in[3];
  const float* tvv = (const float*)d_in[4];
  const float* tvh = (const float*)d_in[5];
  float* out = (float*)d_out;
  const int B = in_sizes[0] / (NTOK * 2304);

  unsigned short* ws = (unsigned short*)d_ws;
  size_t qkSz = (size_t)B * 12 * QPAD * 64;
  unsigned short* qbf = ws;
  unsigned short* kbf = ws + qkSz;
  unsigned short* vbf = ws + 2 * qkSz;
  unsigned short* tkb = vbf + qkSz;
  unsigned short* tvb = tkb + (size_t)12 * 2 * 32 * 64;

  prep_x<<<dim3(10, 12, B), 256, 0, stream>>>(x, wts, qbf, kbf, vbf);
  prep_tab<<<dim3(49, 1, 1), 256, 0, stream>>>(wts, tkv, tkh, tvv, tvh, tkb, tvb);
  hma_kernel<<<dim3(10, 12, B), 256, 0, stream>>>(qbf, kbf, vbf, tkb, tvb, wts, out);
}